// Round 3
// baseline (361.947 us; speedup 1.0000x reference)
//
#include <hip/hip_runtime.h>
#include <hip/hip_bf16.h>
#include <cstdint>

#define NNODES 20000
#define NEDGES 640000
#define ETOT   (NEDGES + NNODES)
#define NGROUP 64
#define HC     256
#define DOUT   32

typedef short bf16x8 __attribute__((ext_vector_type(8)));  // 8 bf16 in 4 VGPRs
typedef short s16x4  __attribute__((ext_vector_type(4)));
typedef float f32x4  __attribute__((ext_vector_type(4)));
typedef float f32x2  __attribute__((ext_vector_type(2)));
typedef int   s32x4  __attribute__((ext_vector_type(4)));
typedef unsigned int u32x4 __attribute__((ext_vector_type(4)));

__device__ __forceinline__ float b2f(__hip_bfloat16 v) { return __bfloat162float(v); }
__device__ __forceinline__ float bs2f(short v) {
    union { unsigned int u; float f; } c; c.u = ((unsigned int)(unsigned short)v) << 16; return c.f;
}
__device__ __forceinline__ short f2bs(float v) {
    __hip_bfloat16 b = __float2bfloat16(v);
    union { __hip_bfloat16 b; short s; } u; u.b = b; return u.s;
}
// float load robust to fp32 vs bf16 storage
__device__ __forceinline__ float ldf(const void* __restrict__ p, size_t i, int bf) {
    return bf ? __bfloat162float(((const __hip_bfloat16*)p)[i]) : ((const float*)p)[i];
}
// int load robust to int32 vs int64 storage (little-endian low word)
__device__ __forceinline__ int ld_idx(const int* __restrict__ p, size_t i, int f64) {
    return f64 ? p[2 * i] : p[i];
}

// ---------------- probe (ballot-parallel) + deg zero ----------------
// flag[0]: edge_index int64?  flag[1]: floats bf16?
__global__ void k_probe(const unsigned int* __restrict__ xw, const int* __restrict__ ei,
                        int* __restrict__ flag, int* __restrict__ deg) {
    int t = blockIdx.x * 256 + threadIdx.x;
    for (int i = t; i < NNODES; i += 256 * 32) deg[i] = 0;
    if (blockIdx.x == 0 && threadIdx.x < 64) {
        int l = threadIdx.x;
        int ones = 0, zeros = 0;
#pragma unroll
        for (int r = 0; r < 4; r++) {
            unsigned long long b1 = __ballot((xw[r * 64 + l] >> 14) & 1);
            unsigned long long b2 = __ballot(ei[2 * (r * 64 + l) + 1] == 0);
            ones  += __popcll(b1);
            zeros += __popcll(b2);
        }
        if (l == 0) { flag[1] = (ones < 64) ? 1 : 0; flag[0] = (zeros > 200) ? 1 : 0; }
    }
}

// ---------------- CSR build over dst ----------------
__global__ void k_hist(const int* __restrict__ ei, int* __restrict__ deg,
                       const int* __restrict__ flag) {
    int i = blockIdx.x * blockDim.x + threadIdx.x;
    if (i >= ETOT) return;
    int f = flag[0];
    int d = (i < NEDGES) ? ld_idx(ei, (size_t)NEDGES + i, f) : (i - NEDGES);
    atomicAdd(&deg[d], 1);
}

// Wave-cooperative coalesced scan: each wave owns a contiguous 2560-node chunk,
// processed 64 nodes at a time (coalesced load, shuffle-scan, coalesced store).
__global__ void k_scan(const int* __restrict__ deg, int* __restrict__ off, int* __restrict__ cur,
                       float* __restrict__ sx, int* __restrict__ cnt) {
    __shared__ int wsum[8];
    int t = threadIdx.x, lane = t & 63, wv = t >> 6;
    for (int i = t; i < NGROUP * HC; i += 512) sx[i] = 0.f;  // zero group sums
    if (t < NGROUP) cnt[t] = 0;                              // zero group counts
    const int CH = ((NNODES + 511) / 512) * 64;              // 2560 per wave
    int base = wv * CH;
    // pass 1: per-wave total
    int s = 0;
    for (int i0 = 0; i0 < CH; i0 += 64) {
        int i = base + i0 + lane;
        s += (i < NNODES) ? deg[i] : 0;
    }
#pragma unroll
    for (int o = 1; o < 64; o <<= 1) s += __shfl_xor(s, o);
    if (lane == 0) wsum[wv] = s;
    __syncthreads();
    int run = 0;
    for (int i = 0; i < wv; i++) run += wsum[i];
    // pass 2: 64-wide inclusive shuffle scan per step, coalesced writes
    for (int i0 = 0; i0 < CH; i0 += 64) {
        int i = base + i0 + lane;
        int v = (i < NNODES) ? deg[i] : 0;
        int sc = v;
#pragma unroll
        for (int o = 1; o < 64; o <<= 1) {
            int u = __shfl_up(sc, o);
            if (lane >= o) sc += u;
        }
        if (i < NNODES) { int ex = run + sc - v; off[i] = ex; cur[i] = ex; }
        run += __shfl(sc, 63);
    }
    if (t == 0) off[NNODES] = ETOT;
}

__global__ void k_scatter(const int* __restrict__ ei, int* __restrict__ cur,
                          int* __restrict__ csr, const int* __restrict__ flag) {
    int i = blockIdx.x * blockDim.x + threadIdx.x;
    if (i >= ETOT) return;
    int f = flag[0];
    int s, d;
    if (i < NEDGES) { s = ld_idx(ei, i, f); d = ld_idx(ei, (size_t)NEDGES + i, f); }
    else            { s = d = i - NEDGES; }
    int pos = atomicAdd(&cur[d], 1);
    csr[pos] = s;
}

// ---------------- both weight transposes, one launch ----------------
__global__ void k_wt(const void* __restrict__ W1, const void* __restrict__ W2,
                     __hip_bfloat16* __restrict__ Wt1, __hip_bfloat16* __restrict__ Wt2,
                     const int* __restrict__ flag) {
    int i = blockIdx.x * 256 + threadIdx.x;  // 131072
    int which = i >> 16;
    int j = i & 65535;
    int k = j >> 8, n = j & 255;
    const void* W = which ? W2 : W1;
    __hip_bfloat16* Wt = which ? Wt2 : Wt1;
    Wt[(size_t)n * 256 + k] = __float2bfloat16(ldf(W, (size_t)k * 256 + n, flag[1]));
}

// ---------------- GEMM (16-row blocks, wave = one head's 64 cols) ----------------
// Block = 16 rows x 256 cols, 4 waves; wave w owns cols [w*64, w*64+64) == head w.
// Grid = 1250 blocks (4.9 blocks/CU) -> latency hiding via occupancy.
// Head alignment makes the fused es/ed epilogue fully wave-local (no LDS reduce).
// A frag: lane holds A[m=lane&15][k=(lane>>4)*8+j]; B mirrors with n=lane&15.
// D frag: col=lane&15, row=(lane>>4)*4+reg (m89/m91-verified).
__global__ __launch_bounds__(256) void k_gemm(const void* __restrict__ A,
                                              const __hip_bfloat16* __restrict__ Bt,
                                              __hip_bfloat16* __restrict__ Hout,
                                              const void* __restrict__ a_src,
                                              const void* __restrict__ a_dst,
                                              float* __restrict__ es4, float* __restrict__ ed4,
                                              const int* __restrict__ flag, int force_bf) {
    int bf   = flag[1];
    int abf  = force_bf | bf;
    int w    = threadIdx.x >> 6;
    int lane = threadIdx.x & 63;
    int mr   = lane & 15;
    int quad = lane >> 4;
    int r0   = blockIdx.x * 16;
    if (r0 >= NNODES) return;
    f32x4 acc[4];
#pragma unroll
    for (int j = 0; j < 4; j++) acc[j] = (f32x4){0.f, 0.f, 0.f, 0.f};
    size_t rowoff = (size_t)(r0 + mr) * HC;
    const __hip_bfloat16* Btw = Bt + (size_t)w * 64 * HC;
    for (int kk = 0; kk < HC; kk += 32) {
        bf16x8 a;
        if (abf) {
            a = *reinterpret_cast<const bf16x8*>((const __hip_bfloat16*)A + rowoff + kk + quad * 8);
        } else {
            const float* af = (const float*)A + rowoff + kk + quad * 8;
            f32x4 lo = *reinterpret_cast<const f32x4*>(af);
            f32x4 hi = *reinterpret_cast<const f32x4*>(af + 4);
#pragma unroll
            for (int ii = 0; ii < 4; ii++) { a[ii] = f2bs(lo[ii]); a[ii + 4] = f2bs(hi[ii]); }
        }
#pragma unroll
        for (int j = 0; j < 4; j++) {
            bf16x8 b = *reinterpret_cast<const bf16x8*>(Btw + (size_t)(j * 16 + mr) * HC + kk + quad * 8);
            acc[j] = __builtin_amdgcn_mfma_f32_16x16x32_bf16(a, b, acc[j], 0, 0, 0);
        }
    }
    // store H (bf16): cols w*64 + j*16 + mr
#pragma unroll
    for (int j = 0; j < 4; j++)
#pragma unroll
        for (int r = 0; r < 4; r++)
            Hout[(size_t)(r0 + quad * 4 + r) * HC + w * 64 + j * 16 + mr] = __float2bfloat16(acc[j][r]);
    // fused scores for head w only: es[row][w] = sum over head-w cols of h*a_src
    float ps[4] = {0.f, 0.f, 0.f, 0.f}, pd[4] = {0.f, 0.f, 0.f, 0.f};
#pragma unroll
    for (int j = 0; j < 4; j++) {
        float asv = ldf(a_src, (size_t)(w * 64 + j * 16 + mr), bf);
        float adv = ldf(a_dst, (size_t)(w * 64 + j * 16 + mr), bf);
#pragma unroll
        for (int r = 0; r < 4; r++) {
            ps[r] = fmaf(acc[j][r], asv, ps[r]);
            pd[r] = fmaf(acc[j][r], adv, pd[r]);
        }
    }
#pragma unroll
    for (int o = 1; o < 16; o <<= 1)
#pragma unroll
        for (int r = 0; r < 4; r++) {
            ps[r] += __shfl_xor(ps[r], o);
            pd[r] += __shfl_xor(pd[r], o);
        }
    if (mr == 0)
#pragma unroll
        for (int r = 0; r < 4; r++) {
            int row = r0 + quad * 4 + r;
            es4[(size_t)row * 4 + w] = ps[r];
            ed4[(size_t)row * 4 + w] = pd[r];
        }
}

// ---------------- score kernel: per-edge softmax weights, precomputed ----------------
// Wave per node (persistent: 2500 blocks x 4 waves x 2 nodes). Two passes over the
// edge list: (1) global max per head, (2) exp(e-m), coalesced alpha write, sum.
// Emits alpha[ETOT][4] (f32, CSR edge order) and rinv4[N][4] = 1/denom.
__global__ __launch_bounds__(256) void k_score(const float* __restrict__ es4,
                                               const float* __restrict__ ed4,
                                               const int* __restrict__ off, const int* __restrict__ csr,
                                               float* __restrict__ alpha, float* __restrict__ rinv4) {
    int wv = threadIdx.x >> 6;
    int l  = threadIdx.x & 63;
    int n0 = blockIdx.x * 4 + wv;
    for (int n = n0; n < NNODES; n += 10000) {
        int base = off[n], deg = off[n + 1] - base;
        f32x4 edv = *reinterpret_cast<const f32x4*>(ed4 + (size_t)n * 4);
        f32x4 m = (f32x4){-INFINITY, -INFINITY, -INFINITY, -INFINITY};
        for (int c0 = 0; c0 < deg; c0 += 64) {
            int cn = min(deg - c0, 64);
            f32x4 ev;
            if (l < cn) {
                int s = csr[base + c0 + l];
                f32x4 e = *reinterpret_cast<const f32x4*>(es4 + (size_t)s * 4);
#pragma unroll
                for (int h = 0; h < 4; h++) {
                    float t = e[h] + edv[h];
                    ev[h] = (t > 0.f) ? t : 0.2f * t;
                }
            } else {
#pragma unroll
                for (int h = 0; h < 4; h++) ev[h] = -INFINITY;
            }
#pragma unroll
            for (int o = 32; o; o >>= 1)
#pragma unroll
                for (int h = 0; h < 4; h++) ev[h] = fmaxf(ev[h], __shfl_xor(ev[h], o));
#pragma unroll
            for (int h = 0; h < 4; h++) m[h] = fmaxf(m[h], ev[h]);
        }
        f32x4 ds = (f32x4){0.f, 0.f, 0.f, 0.f};
        for (int c0 = 0; c0 < deg; c0 += 64) {
            int cn = min(deg - c0, 64);
            f32x4 pv;
            if (l < cn) {
                int s = csr[base + c0 + l];
                f32x4 e = *reinterpret_cast<const f32x4*>(es4 + (size_t)s * 4);
#pragma unroll
                for (int h = 0; h < 4; h++) {
                    float t = e[h] + edv[h];
                    t = (t > 0.f) ? t : 0.2f * t;
                    pv[h] = __expf(t - m[h]);
                }
                *reinterpret_cast<f32x4*>(alpha + (size_t)(base + c0 + l) * 4) = pv;
            } else {
#pragma unroll
                for (int h = 0; h < 4; h++) pv[h] = 0.f;
            }
#pragma unroll
            for (int o = 32; o; o >>= 1)
#pragma unroll
                for (int h = 0; h < 4; h++) pv[h] += __shfl_xor(pv[h], o);
#pragma unroll
            for (int h = 0; h < 4; h++) ds[h] += pv[h];
        }
        if (l == 0) {
            f32x4 rv;
#pragma unroll
            for (int h = 0; h < 4; h++) rv[h] = 1.0f / fmaxf(ds[h], 1e-16f);
            *reinterpret_cast<f32x4*>(rinv4 + (size_t)n * 4) = rv;
        }
    }
}

// ---------------- aggregation: pure weighted gather (softmax precomputed) ----------------
// Persistent: 2500 blocks x 4 waves, 2 nodes/wave. Per chunk: coalesced csr+alpha
// load -> LDS (planar p_lds[h][e]); gather: lane covers 8 cols (16B), half-waves
// take 8 CONSECUTIVE edges each -> src/weight via 4x ds_read_b128 per 16-edge step.
// Accumulate in packed f32x2 (v_pk_fma_f32). No softmax, no exp, no online rescale:
// alpha is globally normalized; rinv applied once at the end.
__global__ __launch_bounds__(256) void k_agg(const __hip_bfloat16* __restrict__ Hb,
                                             const float* __restrict__ alpha,
                                             const float* __restrict__ rinv4,
                                             const void* __restrict__ bias,
                                             const int* __restrict__ off, const int* __restrict__ csr,
                                             const int* __restrict__ flag,
                                             __hip_bfloat16* __restrict__ out) {
    __shared__ float p_lds[4][4][64];  // [wave][head][edge]
    __shared__ int   s_lds[4][64];
    int wv = threadIdx.x >> 6;
    int l  = threadIdx.x & 63;
    int half = l >> 5;
    int hl   = l & 31;
    int hd8  = hl >> 3;               // head owning cols hl*8..hl*8+7
    int bf = flag[1];
    int n0 = blockIdx.x * 4 + wv;
    for (int n = n0; n < NNODES; n += 10000) {
        int base = off[n], deg = off[n + 1] - base;
        f32x2 acc2[4];
#pragma unroll
        for (int d = 0; d < 4; d++) acc2[d] = (f32x2){0.f, 0.f};
        for (int c0 = 0; c0 < deg; c0 += 64) {
            int cn = min(deg - c0, 64);
            int s = 0;
            f32x4 a4 = (f32x4){0.f, 0.f, 0.f, 0.f};
            if (l < cn) {
                s  = csr[base + c0 + l];
                a4 = *reinterpret_cast<const f32x4*>(alpha + (size_t)(base + c0 + l) * 4);
            }
            s_lds[wv][l] = s;
#pragma unroll
            for (int h = 0; h < 4; h++) p_lds[wv][h][l] = a4[h];
            int jn = (cn + 15) & ~15;
            for (int j = 0; j < jn; j += 16) {
                int e0 = j + 8 * half;
                s32x4 sA = *reinterpret_cast<const s32x4*>(&s_lds[wv][e0]);
                s32x4 sB = *reinterpret_cast<const s32x4*>(&s_lds[wv][e0 + 4]);
                f32x4 pA = *reinterpret_cast<const f32x4*>(&p_lds[wv][hd8][e0]);
                f32x4 pB = *reinterpret_cast<const f32x4*>(&p_lds[wv][hd8][e0 + 4]);
                u32x4 hv[8];
#pragma unroll
                for (int i = 0; i < 8; i++) {
                    int sj = (i < 4) ? sA[i & 3] : sB[i & 3];
                    hv[i] = *reinterpret_cast<const u32x4*>(Hb + (size_t)sj * HC + hl * 8);
                }
#pragma unroll
                for (int i = 0; i < 8; i++) {
                    float p = (i < 4) ? pA[i & 3] : pB[i & 3];
#pragma unroll
                    for (int d = 0; d < 4; d++) {
                        unsigned int u = hv[i][d];
                        f32x2 h2;
                        h2.x = __uint_as_float(u << 16);
                        h2.y = __uint_as_float(u & 0xFFFF0000u);
                        acc2[d] += h2 * p;
                    }
                }
            }
        }
        // merge half-accumulators
#pragma unroll
        for (int d = 0; d < 4; d++) {
            acc2[d].x += __shfl_xor(acc2[d].x, 32);
            acc2[d].y += __shfl_xor(acc2[d].y, 32);
        }
        f32x4 rv = *reinterpret_cast<const f32x4*>(rinv4 + (size_t)n * 4);
        float rinv = rv[hd8];
        if (half == 0) {
            bf16x8 ov;
#pragma unroll
            for (int d = 0; d < 4; d++) {
                float v0 = acc2[d].x * rinv + ldf(bias, (size_t)hl * 8 + 2 * d, bf);
                float v1 = acc2[d].y * rinv + ldf(bias, (size_t)hl * 8 + 2 * d + 1, bf);
                ov[2 * d]     = f2bs(fmaxf(v0, 0.f));
                ov[2 * d + 1] = f2bs(fmaxf(v1, 0.f));
            }
            *reinterpret_cast<bf16x8*>(out + (size_t)n * HC + hl * 8) = ov;
        }
    }
}

// ---------------- readout: 4-row-parallel boundary-flush group sums + counts ----------------
__global__ __launch_bounds__(256) void k_groupsum(const __hip_bfloat16* __restrict__ X2,
                                                  const int* __restrict__ batch,
                                                  float* __restrict__ sx, int* __restrict__ cnt,
                                                  const int* __restrict__ flag) {
    const int RPB = NNODES / 250;  // 80
    int b = blockIdx.x, f = flag[0];
    int sub = threadIdx.x >> 6, l = threadIdx.x & 63;
    int r = b * RPB + sub;
    f32x4 acc = (f32x4){0.f, 0.f, 0.f, 0.f};
    int curg = ld_idx(batch, r, f);
    int cacc = 0;
    for (int k = 0; k < RPB / 4; k++, r += 4) {
        int g = ld_idx(batch, r, f);
        if (g != curg) {
#pragma unroll
            for (int c = 0; c < 4; c++) atomicAdd(&sx[(size_t)curg * HC + l * 4 + c], acc[c]);
            if (l == 0) atomicAdd(&cnt[curg], cacc);
            acc = (f32x4){0.f, 0.f, 0.f, 0.f}; cacc = 0; curg = g;
        }
        s16x4 hv = *reinterpret_cast<const s16x4*>(X2 + (size_t)r * HC + l * 4);
#pragma unroll
        for (int c = 0; c < 4; c++) acc[c] += bs2f(hv[c]);
        cacc++;
    }
#pragma unroll
    for (int c = 0; c < 4; c++) atomicAdd(&sx[(size_t)curg * HC + l * 4 + c], acc[c]);
    if (l == 0) atomicAdd(&cnt[curg], cacc);
}

// ---------------- final projection: one block per group, 8-way split dot + LDS reduce --------
__global__ __launch_bounds__(256) void k_final(const float* __restrict__ sx,
                                               const void* __restrict__ Wp,
                                               const void* __restrict__ bp,
                                               const int* __restrict__ cnt,
                                               const int* __restrict__ flag,
                                               void* __restrict__ out) {
    __shared__ float red[8][32];
    int g = blockIdx.x, t = threadIdx.x;
    int c = t & 31, seg = t >> 5;
    int bf = flag[1];
    const float* sxg = sx + (size_t)g * HC;
    float a = 0.f;
#pragma unroll
    for (int k = 0; k < 32; k++) {
        int kk = seg * 32 + k;
        a = fmaf(sxg[kk], ldf(Wp, (size_t)kk * DOUT + c, bf), a);
    }
    red[seg][c] = a;
    __syncthreads();
    if (t < 32) {
        float s = 0.f;
#pragma unroll
        for (int i = 0; i < 8; i++) s += red[i][t];
        int ct = cnt[g];
        float v = (ct > 0) ? (s / ct + ldf(bp, (size_t)t, bf)) : 0.f;
        if (bf) ((__hip_bfloat16*)out)[g * DOUT + t] = __float2bfloat16(v);
        else    ((float*)out)[g * DOUT + t]          = v;
    }
}

extern "C" void kernel_launch(void* const* d_in, const int* in_sizes, int n_in,
                              void* d_out, int out_size, void* d_ws, size_t ws_size,
                              hipStream_t stream) {
    (void)in_sizes; (void)n_in; (void)out_size; (void)ws_size;
    const void* x   = d_in[0];
    const int*  ei  = (const int*)d_in[1];
    const int*  bat = (const int*)d_in[2];
    const void* W1  = d_in[3];
    const void* as1 = d_in[4];
    const void* ad1 = d_in[5];
    const void* b1  = d_in[6];
    const void* W2  = d_in[7];
    const void* as2 = d_in[8];
    const void* ad2 = d_in[9];
    const void* b2  = d_in[10];
    const void* Wp  = d_in[11];
    const void* bp  = d_in[12];

    char* ws = (char*)d_ws;
    size_t o = 0;
    auto alloc = [&](size_t bytes) -> char* {
        char* p = ws + o;
        o += (bytes + 255) & ~(size_t)255;
        return p;
    };
    __hip_bfloat16* hb  = (__hip_bfloat16*)alloc((size_t)NNODES * HC * 2);  // bf16 h
    __hip_bfloat16* xb  = (__hip_bfloat16*)alloc((size_t)NNODES * HC * 2);  // bf16 layer-1 out
    __hip_bfloat16* xb2 = (__hip_bfloat16*)alloc((size_t)NNODES * HC * 2);  // bf16 layer-2 out
    __hip_bfloat16* Wt1 = (__hip_bfloat16*)alloc((size_t)HC * HC * 2);
    __hip_bfloat16* Wt2 = (__hip_bfloat16*)alloc((size_t)HC * HC * 2);
    float* es = (float*)alloc((size_t)NNODES * 4 * 4);
    float* ed = (float*)alloc((size_t)NNODES * 4 * 4);
    float* alpha = (float*)alloc((size_t)ETOT * 4 * 4);    // per-edge weights (CSR order)
    float* rinv  = (float*)alloc((size_t)NNODES * 4 * 4);  // 1/denom per node per head
    int* deg  = (int*)alloc((size_t)NNODES * 4);
    int* cur  = (int*)alloc((size_t)NNODES * 4);
    int* off  = (int*)alloc((size_t)(NNODES + 1) * 4);
    int* csr  = (int*)alloc((size_t)ETOT * 4);
    float* sx = (float*)alloc((size_t)NGROUP * HC * 4);
    int* cnt  = (int*)alloc(256);
    int* flag = (int*)alloc(256);

    // probe + CSR (shared by both layers)
    k_probe<<<32, 256, 0, stream>>>((const unsigned int*)x, ei, flag, deg);
    k_hist<<<(ETOT + 255) / 256, 256, 0, stream>>>(ei, deg, flag);
    k_scan<<<1, 512, 0, stream>>>(deg, off, cur, sx, cnt);
    k_scatter<<<(ETOT + 255) / 256, 256, 0, stream>>>(ei, cur, csr, flag);
    k_wt<<<512, 256, 0, stream>>>(W1, W2, Wt1, Wt2, flag);

    // Layer 1
    k_gemm<<<NNODES / 16, 256, 0, stream>>>(x, Wt1, hb, as1, ad1, es, ed, flag, 0);
    k_score<<<2500, 256, 0, stream>>>(es, ed, off, csr, alpha, rinv);
    k_agg<<<2500, 256, 0, stream>>>(hb, alpha, rinv, b1, off, csr, flag, xb);

    // Layer 2
    k_gemm<<<NNODES / 16, 256, 0, stream>>>(xb, Wt2, hb, as2, ad2, es, ed, flag, 1);
    k_score<<<2500, 256, 0, stream>>>(es, ed, off, csr, alpha, rinv);
    k_agg<<<2500, 256, 0, stream>>>(hb, alpha, rinv, b2, off, csr, flag, xb2);

    // Readout
    k_groupsum<<<250, 256, 0, stream>>>(xb2, bat, sx, cnt, flag);
    k_final<<<NGROUP, 256, 0, stream>>>(sx, Wp, bp, cnt, flag, d_out);
}

// Round 4
// 320.415 us; speedup vs baseline: 1.1296x; 1.1296x over previous
//
#include <hip/hip_runtime.h>
#include <hip/hip_bf16.h>
#include <cstdint>

#define NNODES 20000
#define NEDGES 640000
#define ETOT   (NEDGES + NNODES)
#define NGROUP 64
#define HC     256
#define DOUT   32
#define NB     128                      // CSR-build blocks
#define SL     ((ETOT + NB - 1) / NB)   // 5157 edges per block slice

typedef short bf16x8 __attribute__((ext_vector_type(8)));  // 8 bf16 in 4 VGPRs
typedef short s16x4  __attribute__((ext_vector_type(4)));
typedef float f32x4  __attribute__((ext_vector_type(4)));
typedef float f32x2  __attribute__((ext_vector_type(2)));
typedef int   s32x4  __attribute__((ext_vector_type(4)));
typedef unsigned int u32x4 __attribute__((ext_vector_type(4)));

__device__ __forceinline__ float b2f(__hip_bfloat16 v) { return __bfloat162float(v); }
__device__ __forceinline__ float bs2f(short v) {
    union { unsigned int u; float f; } c; c.u = ((unsigned int)(unsigned short)v) << 16; return c.f;
}
__device__ __forceinline__ short f2bs(float v) {
    __hip_bfloat16 b = __float2bfloat16(v);
    union { __hip_bfloat16 b; short s; } u; u.b = b; return u.s;
}
// float load robust to fp32 vs bf16 storage
__device__ __forceinline__ float ldf(const void* __restrict__ p, size_t i, int bf) {
    return bf ? __bfloat162float(((const __hip_bfloat16*)p)[i]) : ((const float*)p)[i];
}
// int load robust to int32 vs int64 storage (little-endian low word)
__device__ __forceinline__ int ld_idx(const int* __restrict__ p, size_t i, int f64) {
    return f64 ? p[2 * i] : p[i];
}

// ---------------- probe (ballot-parallel) ----------------
// flag[0]: edge_index int64?  flag[1]: floats bf16?
__global__ void k_probe(const unsigned int* __restrict__ xw, const int* __restrict__ ei,
                        int* __restrict__ flag) {
    if (threadIdx.x < 64) {
        int l = threadIdx.x;
        int ones = 0, zeros = 0;
#pragma unroll
        for (int r = 0; r < 4; r++) {
            unsigned long long b1 = __ballot((xw[r * 64 + l] >> 14) & 1);
            unsigned long long b2 = __ballot(ei[2 * (r * 64 + l) + 1] == 0);
            ones  += __popcll(b1);
            zeros += __popcll(b2);
        }
        if (l == 0) { flag[1] = (ones < 64) ? 1 : 0; flag[0] = (zeros > 200) ? 1 : 0; }
    }
}

// ---------------- CSR build, atomic-free (per-block LDS histograms) ----------------
// Phase A: block b histograms its edge slice into LDS (20000 u32 = 80 KB), then
// writes the local histogram coalesced to H[b][0..NNODES).
__global__ __launch_bounds__(256) void k_lhist(const int* __restrict__ ei,
                                               int* __restrict__ H,
                                               const int* __restrict__ flag) {
    __shared__ int hl[NNODES];  // 80 KB
    int t = threadIdx.x, b = blockIdx.x, f = flag[0];
    for (int i = t; i < NNODES; i += 256) hl[i] = 0;
    __syncthreads();
    int s0 = b * SL, s1 = min(s0 + SL, ETOT);
    for (int i = s0 + t; i < s1; i += 256) {
        int d = (i < NEDGES) ? ld_idx(ei, (size_t)NEDGES + i, f) : (i - NEDGES);
        atomicAdd(&hl[d], 1);
    }
    __syncthreads();
    int* Hb = H + (size_t)b * NNODES;
    for (int i = t; i < NNODES; i += 256) Hb[i] = hl[i];
}

// Phase B1: deg[n] = sum over blocks of H[b][n] (coalesced per b).
__global__ __launch_bounds__(256) void k_colsum(const int* __restrict__ H,
                                                int* __restrict__ deg) {
    int n = blockIdx.x * 256 + threadIdx.x;
    if (n >= NNODES) return;
    int s = 0;
#pragma unroll 4
    for (int b = 0; b < NB; b++) s += H[(size_t)b * NNODES + n];
    deg[n] = s;
}

// Phase B2: single-block scan deg -> off (wave-cooperative, coalesced); also zeros
// the group-sum buffers for the readout.
__global__ void k_scan(const int* __restrict__ deg, int* __restrict__ off,
                       float* __restrict__ sx, int* __restrict__ cnt) {
    __shared__ int wsum[8];
    int t = threadIdx.x, lane = t & 63, wv = t >> 6;
    for (int i = t; i < NGROUP * HC; i += 512) sx[i] = 0.f;
    if (t < NGROUP) cnt[t] = 0;
    const int CH = ((NNODES + 511) / 512) * 64;  // 2560 per wave
    int base = wv * CH;
    int s = 0;
    for (int i0 = 0; i0 < CH; i0 += 64) {
        int i = base + i0 + lane;
        s += (i < NNODES) ? deg[i] : 0;
    }
#pragma unroll
    for (int o = 1; o < 64; o <<= 1) s += __shfl_xor(s, o);
    if (lane == 0) wsum[wv] = s;
    __syncthreads();
    int run = 0;
    for (int i = 0; i < wv; i++) run += wsum[i];
    for (int i0 = 0; i0 < CH; i0 += 64) {
        int i = base + i0 + lane;
        int v = (i < NNODES) ? deg[i] : 0;
        int sc = v;
#pragma unroll
        for (int o = 1; o < 64; o <<= 1) {
            int u = __shfl_up(sc, o);
            if (lane >= o) sc += u;
        }
        if (i < NNODES) off[i] = run + sc - v;
        run += __shfl(sc, 63);
    }
    if (t == 0) off[NNODES] = ETOT;
}

// Phase B3: in-place 2D prefix: H[b][n] <- off[n] + sum_{b'<b} H[b'][n]
// (global start of block b's run for node n).
__global__ __launch_bounds__(256) void k_base(int* __restrict__ H,
                                              const int* __restrict__ off) {
    int n = blockIdx.x * 256 + threadIdx.x;
    if (n >= NNODES) return;
    int run = off[n];
#pragma unroll 4
    for (int b = 0; b < NB; b++) {
        size_t idx = (size_t)b * NNODES + n;
        int t = H[idx];
        H[idx] = run;
        run += t;
    }
}

// Phase C: re-read slice; position via LDS atomic on the per-block base array
// (loaded from H[b][...]); plain scattered csr store. Zero global atomics.
__global__ __launch_bounds__(256) void k_scatter2(const int* __restrict__ ei,
                                                  const int* __restrict__ H,
                                                  int* __restrict__ csr,
                                                  const int* __restrict__ flag) {
    __shared__ int base_l[NNODES];  // 80 KB
    int t = threadIdx.x, b = blockIdx.x, f = flag[0];
    const int* Hb = H + (size_t)b * NNODES;
    for (int i = t; i < NNODES; i += 256) base_l[i] = Hb[i];
    __syncthreads();
    int s0 = b * SL, s1 = min(s0 + SL, ETOT);
    for (int i = s0 + t; i < s1; i += 256) {
        int s, d;
        if (i < NEDGES) { s = ld_idx(ei, i, f); d = ld_idx(ei, (size_t)NEDGES + i, f); }
        else            { s = d = i - NEDGES; }
        int pos = atomicAdd(&base_l[d], 1);
        csr[pos] = s;
    }
}

// ---------------- both weight transposes, one launch ----------------
__global__ void k_wt(const void* __restrict__ W1, const void* __restrict__ W2,
                     __hip_bfloat16* __restrict__ Wt1, __hip_bfloat16* __restrict__ Wt2,
                     const int* __restrict__ flag) {
    int i = blockIdx.x * 256 + threadIdx.x;  // 131072
    int which = i >> 16;
    int j = i & 65535;
    int k = j >> 8, n = j & 255;
    const void* W = which ? W2 : W1;
    __hip_bfloat16* Wt = which ? Wt2 : Wt1;
    Wt[(size_t)n * 256 + k] = __float2bfloat16(ldf(W, (size_t)k * 256 + n, flag[1]));
}

// ---------------- GEMM (16-row blocks, wave = one head's 64 cols) ----------------
// Block = 16 rows x 256 cols, 4 waves; wave w owns cols [w*64, w*64+64) == head w.
// Grid = 1250 blocks (4.9 blocks/CU) -> latency hiding via occupancy.
// Head alignment makes the fused es/ed epilogue fully wave-local (no LDS reduce).
// A frag: lane holds A[m=lane&15][k=(lane>>4)*8+j]; B mirrors with n=lane&15.
// D frag: col=lane&15, row=(lane>>4)*4+reg (m89/m91-verified).
__global__ __launch_bounds__(256) void k_gemm(const void* __restrict__ A,
                                              const __hip_bfloat16* __restrict__ Bt,
                                              __hip_bfloat16* __restrict__ Hout,
                                              const void* __restrict__ a_src,
                                              const void* __restrict__ a_dst,
                                              float* __restrict__ es4, float* __restrict__ ed4,
                                              const int* __restrict__ flag, int force_bf) {
    int bf   = flag[1];
    int abf  = force_bf | bf;
    int w    = threadIdx.x >> 6;
    int lane = threadIdx.x & 63;
    int mr   = lane & 15;
    int quad = lane >> 4;
    int r0   = blockIdx.x * 16;
    if (r0 >= NNODES) return;
    f32x4 acc[4];
#pragma unroll
    for (int j = 0; j < 4; j++) acc[j] = (f32x4){0.f, 0.f, 0.f, 0.f};
    size_t rowoff = (size_t)(r0 + mr) * HC;
    const __hip_bfloat16* Btw = Bt + (size_t)w * 64 * HC;
    for (int kk = 0; kk < HC; kk += 32) {
        bf16x8 a;
        if (abf) {
            a = *reinterpret_cast<const bf16x8*>((const __hip_bfloat16*)A + rowoff + kk + quad * 8);
        } else {
            const float* af = (const float*)A + rowoff + kk + quad * 8;
            f32x4 lo = *reinterpret_cast<const f32x4*>(af);
            f32x4 hi = *reinterpret_cast<const f32x4*>(af + 4);
#pragma unroll
            for (int ii = 0; ii < 4; ii++) { a[ii] = f2bs(lo[ii]); a[ii + 4] = f2bs(hi[ii]); }
        }
#pragma unroll
        for (int j = 0; j < 4; j++) {
            bf16x8 b = *reinterpret_cast<const bf16x8*>(Btw + (size_t)(j * 16 + mr) * HC + kk + quad * 8);
            acc[j] = __builtin_amdgcn_mfma_f32_16x16x32_bf16(a, b, acc[j], 0, 0, 0);
        }
    }
    // store H (bf16): cols w*64 + j*16 + mr
#pragma unroll
    for (int j = 0; j < 4; j++)
#pragma unroll
        for (int r = 0; r < 4; r++)
            Hout[(size_t)(r0 + quad * 4 + r) * HC + w * 64 + j * 16 + mr] = __float2bfloat16(acc[j][r]);
    // fused scores for head w only: es[row][w] = sum over head-w cols of h*a_src
    float ps[4] = {0.f, 0.f, 0.f, 0.f}, pd[4] = {0.f, 0.f, 0.f, 0.f};
#pragma unroll
    for (int j = 0; j < 4; j++) {
        float asv = ldf(a_src, (size_t)(w * 64 + j * 16 + mr), bf);
        float adv = ldf(a_dst, (size_t)(w * 64 + j * 16 + mr), bf);
#pragma unroll
        for (int r = 0; r < 4; r++) {
            ps[r] = fmaf(acc[j][r], asv, ps[r]);
            pd[r] = fmaf(acc[j][r], adv, pd[r]);
        }
    }
#pragma unroll
    for (int o = 1; o < 16; o <<= 1)
#pragma unroll
        for (int r = 0; r < 4; r++) {
            ps[r] += __shfl_xor(ps[r], o);
            pd[r] += __shfl_xor(pd[r], o);
        }
    if (mr == 0)
#pragma unroll
        for (int r = 0; r < 4; r++) {
            int row = r0 + quad * 4 + r;
            es4[(size_t)row * 4 + w] = ps[r];
            ed4[(size_t)row * 4 + w] = pd[r];
        }
}

// ---------------- fused softmax + aggregation (wave per node, persistent) ----------------
// Softmax phase: lane j owns edge j of the 64-edge chunk (online, all 4 heads).
// Gather phase: lane covers 8 cols (16B load); half-waves take 8 CONSECUTIVE edges
// -> indices/weights via ds_read_b128 from planar LDS; packed f32x2 accumulate.
__global__ __launch_bounds__(256) void k_agg(const __hip_bfloat16* __restrict__ Hb,
                                             const float* __restrict__ es4, const float* __restrict__ ed4,
                                             const void* __restrict__ bias,
                                             const int* __restrict__ off, const int* __restrict__ csr,
                                             const int* __restrict__ flag,
                                             __hip_bfloat16* __restrict__ out) {
    __shared__ float p_lds[4][4][64];  // [wave][head][edge]
    __shared__ int   s_lds[4][64];
    int wv = threadIdx.x >> 6;
    int l  = threadIdx.x & 63;
    int half = l >> 5;
    int hl   = l & 31;
    int hd8  = hl >> 3;               // head owning cols hl*8..hl*8+7
    int bf = flag[1];
    int n0 = blockIdx.x * 4 + wv;
    for (int n = n0; n < NNODES; n += 10000) {
        int base = off[n], deg = off[n + 1] - base;
        f32x4 edv = *reinterpret_cast<const f32x4*>(ed4 + (size_t)n * 4);
        f32x4 m    = (f32x4){-INFINITY, -INFINITY, -INFINITY, -INFINITY};
        f32x4 dsum = (f32x4){0.f, 0.f, 0.f, 0.f};
        f32x2 acc2[4];
#pragma unroll
        for (int d = 0; d < 4; d++) acc2[d] = (f32x2){0.f, 0.f};
        for (int c0 = 0; c0 < deg; c0 += 64) {
            int cn = min(deg - c0, 64);
            int s = 0;
            f32x4 ev;
            if (l < cn) {
                s = csr[base + c0 + l];
                f32x4 e = *reinterpret_cast<const f32x4*>(es4 + (size_t)s * 4);
#pragma unroll
                for (int h = 0; h < 4; h++) {
                    float t = e[h] + edv[h];
                    ev[h] = (t > 0.f) ? t : 0.2f * t;
                }
            } else {
#pragma unroll
                for (int h = 0; h < 4; h++) ev[h] = -INFINITY;
            }
            s_lds[wv][l] = s;   // pad lanes -> row 0 (weight 0)
            // wave max per head
            f32x4 mc = ev;
#pragma unroll
            for (int o = 32; o; o >>= 1)
#pragma unroll
                for (int h = 0; h < 4; h++) mc[h] = fmaxf(mc[h], __shfl_xor(mc[h], o));
            // online-softmax update
            f32x4 al, pv;
#pragma unroll
            for (int h = 0; h < 4; h++) {
                float nm = fmaxf(m[h], mc[h]);
                al[h] = __expf(m[h] - nm);   // m=-inf on first chunk -> 0
                m[h]  = nm;
            }
#pragma unroll
            for (int h = 0; h < 4; h++) pv[h] = (l < cn) ? __expf(ev[h] - m[h]) : 0.f;
            f32x4 sc = pv;
#pragma unroll
            for (int o = 32; o; o >>= 1)
#pragma unroll
                for (int h = 0; h < 4; h++) sc[h] += __shfl_xor(sc[h], o);
#pragma unroll
            for (int h = 0; h < 4; h++) dsum[h] = dsum[h] * al[h] + sc[h];
            float a8 = al[hd8];
#pragma unroll
            for (int d = 0; d < 4; d++) acc2[d] *= a8;
#pragma unroll
            for (int h = 0; h < 4; h++) p_lds[wv][h][l] = pv[h];
            // gather: half-waves take 8 consecutive edges each, 16 edges/step
            int jn = (cn + 15) & ~15;
            for (int j = 0; j < jn; j += 16) {
                int e0 = j + 8 * half;
                s32x4 sA = *reinterpret_cast<const s32x4*>(&s_lds[wv][e0]);
                s32x4 sB = *reinterpret_cast<const s32x4*>(&s_lds[wv][e0 + 4]);
                f32x4 pA = *reinterpret_cast<const f32x4*>(&p_lds[wv][hd8][e0]);
                f32x4 pB = *reinterpret_cast<const f32x4*>(&p_lds[wv][hd8][e0 + 4]);
                u32x4 hv[8];
#pragma unroll
                for (int i = 0; i < 8; i++) {
                    int sj = (i < 4) ? sA[i & 3] : sB[i & 3];
                    hv[i] = *reinterpret_cast<const u32x4*>(Hb + (size_t)sj * HC + hl * 8);
                }
#pragma unroll
                for (int i = 0; i < 8; i++) {
                    float p = (i < 4) ? pA[i & 3] : pB[i & 3];
#pragma unroll
                    for (int d = 0; d < 4; d++) {
                        unsigned int u = hv[i][d];
                        f32x2 h2;
                        h2.x = __uint_as_float(u << 16);
                        h2.y = __uint_as_float(u & 0xFFFF0000u);
                        acc2[d] += h2 * p;
                    }
                }
            }
        }
        // merge half-accumulators (scaling is wave-uniform)
#pragma unroll
        for (int d = 0; d < 4; d++) {
            acc2[d].x += __shfl_xor(acc2[d].x, 32);
            acc2[d].y += __shfl_xor(acc2[d].y, 32);
        }
        float rinv = 1.0f / fmaxf(dsum[hd8], 1e-16f);
        if (half == 0) {
            bf16x8 ov;
#pragma unroll
            for (int d = 0; d < 4; d++) {
                float v0 = acc2[d].x * rinv + ldf(bias, (size_t)hl * 8 + 2 * d, bf);
                float v1 = acc2[d].y * rinv + ldf(bias, (size_t)hl * 8 + 2 * d + 1, bf);
                ov[2 * d]     = f2bs(fmaxf(v0, 0.f));
                ov[2 * d + 1] = f2bs(fmaxf(v1, 0.f));
            }
            *reinterpret_cast<bf16x8*>(out + (size_t)n * HC + hl * 8) = ov;
        }
    }
}

// ---------------- readout: 4-row-parallel boundary-flush group sums + counts ----------------
__global__ __launch_bounds__(256) void k_groupsum(const __hip_bfloat16* __restrict__ X2,
                                                  const int* __restrict__ batch,
                                                  float* __restrict__ sx, int* __restrict__ cnt,
                                                  const int* __restrict__ flag) {
    const int RPB = NNODES / 250;  // 80
    int b = blockIdx.x, f = flag[0];
    int sub = threadIdx.x >> 6, l = threadIdx.x & 63;
    int r = b * RPB + sub;
    f32x4 acc = (f32x4){0.f, 0.f, 0.f, 0.f};
    int curg = ld_idx(batch, r, f);
    int cacc = 0;
    for (int k = 0; k < RPB / 4; k++, r += 4) {
        int g = ld_idx(batch, r, f);
        if (g != curg) {
#pragma unroll
            for (int c = 0; c < 4; c++) atomicAdd(&sx[(size_t)curg * HC + l * 4 + c], acc[c]);
            if (l == 0) atomicAdd(&cnt[curg], cacc);
            acc = (f32x4){0.f, 0.f, 0.f, 0.f}; cacc = 0; curg = g;
        }
        s16x4 hv = *reinterpret_cast<const s16x4*>(X2 + (size_t)r * HC + l * 4);
#pragma unroll
        for (int c = 0; c < 4; c++) acc[c] += bs2f(hv[c]);
        cacc++;
    }
#pragma unroll
    for (int c = 0; c < 4; c++) atomicAdd(&sx[(size_t)curg * HC + l * 4 + c], acc[c]);
    if (l == 0) atomicAdd(&cnt[curg], cacc);
}

// ---------------- final projection: one block per group, 8-way split dot + LDS reduce --------
__global__ __launch_bounds__(256) void k_final(const float* __restrict__ sx,
                                               const void* __restrict__ Wp,
                                               const void* __restrict__ bp,
                                               const int* __restrict__ cnt,
                                               const int* __restrict__ flag,
                                               void* __restrict__ out) {
    __shared__ float red[8][32];
    int g = blockIdx.x, t = threadIdx.x;
    int c = t & 31, seg = t >> 5;
    int bf = flag[1];
    const float* sxg = sx + (size_t)g * HC;
    float a = 0.f;
#pragma unroll
    for (int k = 0; k < 32; k++) {
        int kk = seg * 32 + k;
        a = fmaf(sxg[kk], ldf(Wp, (size_t)kk * DOUT + c, bf), a);
    }
    red[seg][c] = a;
    __syncthreads();
    if (t < 32) {
        float s = 0.f;
#pragma unroll
        for (int i = 0; i < 8; i++) s += red[i][t];
        int ct = cnt[g];
        float v = (ct > 0) ? (s / ct + ldf(bp, (size_t)t, bf)) : 0.f;
        if (bf) ((__hip_bfloat16*)out)[g * DOUT + t] = __float2bfloat16(v);
        else    ((float*)out)[g * DOUT + t]          = v;
    }
}

extern "C" void kernel_launch(void* const* d_in, const int* in_sizes, int n_in,
                              void* d_out, int out_size, void* d_ws, size_t ws_size,
                              hipStream_t stream) {
    (void)in_sizes; (void)n_in; (void)out_size; (void)ws_size;
    const void* x   = d_in[0];
    const int*  ei  = (const int*)d_in[1];
    const int*  bat = (const int*)d_in[2];
    const void* W1  = d_in[3];
    const void* as1 = d_in[4];
    const void* ad1 = d_in[5];
    const void* b1  = d_in[6];
    const void* W2  = d_in[7];
    const void* as2 = d_in[8];
    const void* ad2 = d_in[9];
    const void* b2  = d_in[10];
    const void* Wp  = d_in[11];
    const void* bp  = d_in[12];

    char* ws = (char*)d_ws;
    size_t o = 0;
    auto alloc = [&](size_t bytes) -> char* {
        char* p = ws + o;
        o += (bytes + 255) & ~(size_t)255;
        return p;
    };
    __hip_bfloat16* hb  = (__hip_bfloat16*)alloc((size_t)NNODES * HC * 2);  // bf16 h
    __hip_bfloat16* xb  = (__hip_bfloat16*)alloc((size_t)NNODES * HC * 2);  // bf16 layer-1 out
    __hip_bfloat16* xb2 = (__hip_bfloat16*)alloc((size_t)NNODES * HC * 2);  // bf16 layer-2 out
    __hip_bfloat16* Wt1 = (__hip_bfloat16*)alloc((size_t)HC * HC * 2);
    __hip_bfloat16* Wt2 = (__hip_bfloat16*)alloc((size_t)HC * HC * 2);
    float* es = (float*)alloc((size_t)NNODES * 4 * 4);
    float* ed = (float*)alloc((size_t)NNODES * 4 * 4);
    int* H    = (int*)alloc((size_t)NB * NNODES * 4);      // per-block histograms / bases
    int* deg  = (int*)alloc((size_t)NNODES * 4);
    int* off  = (int*)alloc((size_t)(NNODES + 1) * 4);
    int* csr  = (int*)alloc((size_t)ETOT * 4);
    float* sx = (float*)alloc((size_t)NGROUP * HC * 4);
    int* cnt  = (int*)alloc(256);
    int* flag = (int*)alloc(256);

    // probe + atomic-free CSR build (shared by both layers)
    k_probe<<<1, 256, 0, stream>>>((const unsigned int*)x, ei, flag);
    k_lhist<<<NB, 256, 0, stream>>>(ei, H, flag);
    k_colsum<<<(NNODES + 255) / 256, 256, 0, stream>>>(H, deg);
    k_scan<<<1, 512, 0, stream>>>(deg, off, sx, cnt);
    k_base<<<(NNODES + 255) / 256, 256, 0, stream>>>(H, off);
    k_scatter2<<<NB, 256, 0, stream>>>(ei, H, csr, flag);
    k_wt<<<512, 256, 0, stream>>>(W1, W2, Wt1, Wt2, flag);

    // Layer 1
    k_gemm<<<NNODES / 16, 256, 0, stream>>>(x, Wt1, hb, as1, ad1, es, ed, flag, 0);
    k_agg<<<2500, 256, 0, stream>>>(hb, es, ed, b1, off, csr, flag, xb);

    // Layer 2
    k_gemm<<<NNODES / 16, 256, 0, stream>>>(xb, Wt2, hb, as2, ad2, es, ed, flag, 1);
    k_agg<<<2500, 256, 0, stream>>>(hb, es, ed, b2, off, csr, flag, xb2);

    // Readout
    k_groupsum<<<250, 256, 0, stream>>>(xb2, bat, sx, cnt, flag);
    k_final<<<NGROUP, 256, 0, stream>>>(sx, Wp, bp, cnt, flag, d_out);
}

// Round 5
// 299.685 us; speedup vs baseline: 1.2078x; 1.0692x over previous
//
#include <hip/hip_runtime.h>
#include <hip/hip_bf16.h>
#include <cstdint>

#define NNODES 20000
#define NEDGES 640000
#define ETOT   (NEDGES + NNODES)
#define NGROUP 64
#define HC     256
#define DOUT   32
#define EBLK   5120                     // edges per CSR-build block (divides NEDGES)
#define NBLK   (NEDGES / EBLK)          // 125
#define CBLK   ((NNODES + 255) / 256)   // 79 node blocks

typedef short bf16x8 __attribute__((ext_vector_type(8)));  // 8 bf16 in 4 VGPRs
typedef short s16x4  __attribute__((ext_vector_type(4)));
typedef float f32x4  __attribute__((ext_vector_type(4)));
typedef float f32x2  __attribute__((ext_vector_type(2)));
typedef int   s32x4  __attribute__((ext_vector_type(4)));
typedef unsigned int u32x4 __attribute__((ext_vector_type(4)));

__device__ __forceinline__ float b2f(__hip_bfloat16 v) { return __bfloat162float(v); }
__device__ __forceinline__ float bs2f(short v) {
    union { unsigned int u; float f; } c; c.u = ((unsigned int)(unsigned short)v) << 16; return c.f;
}
__device__ __forceinline__ short f2bs(float v) {
    __hip_bfloat16 b = __float2bfloat16(v);
    union { __hip_bfloat16 b; short s; } u; u.b = b; return u.s;
}
// float load robust to fp32 vs bf16 storage
__device__ __forceinline__ float ldf(const void* __restrict__ p, size_t i, int bf) {
    return bf ? __bfloat162float(((const __hip_bfloat16*)p)[i]) : ((const float*)p)[i];
}
// int load robust to int32 vs int64 storage (little-endian low word)
__device__ __forceinline__ int ld_idx(const int* __restrict__ p, size_t i, int f64) {
    return f64 ? p[2 * i] : p[i];
}

// ---------------- probe (ballot-parallel) + readout-buffer zero ----------------
// flag[0]: edge_index int64?  flag[1]: floats bf16?
__global__ void k_probe(const unsigned int* __restrict__ xw, const int* __restrict__ ei,
                        int* __restrict__ flag, float* __restrict__ sx, int* __restrict__ cnt) {
    int t = threadIdx.x;
    for (int i = t; i < NGROUP * HC; i += 256) sx[i] = 0.f;
    if (t < NGROUP) cnt[t] = 0;
    if (t < 64) {
        int l = t;
        int ones = 0, zeros = 0;
#pragma unroll
        for (int r = 0; r < 4; r++) {
            unsigned long long b1 = __ballot((xw[r * 64 + l] >> 14) & 1);
            unsigned long long b2 = __ballot(ei[2 * (r * 64 + l) + 1] == 0);
            ones  += __popcll(b1);
            zeros += __popcll(b2);
        }
        if (l == 0) { flag[1] = (ones < 64) ? 1 : 0; flag[0] = (zeros > 200) ? 1 : 0; }
    }
}

// ---------------- CSR build, atomic-free (per-block LDS histograms) ----------------
// Self-loops are NOT histogrammed: deg = colsum + 1 and csr[off[n]] = n is written
// directly by k_base. Each block handles exactly EBLK real edges -> no guards,
// 16B-aligned dwordx4 edge loads.
__global__ __launch_bounds__(256) void k_lhist(const int* __restrict__ ei,
                                               int* __restrict__ H,
                                               const int* __restrict__ flag) {
    __shared__ int hl[NNODES];  // 80 KB
    int t = threadIdx.x, b = blockIdx.x, f = flag[0];
    s32x4* hl4 = reinterpret_cast<s32x4*>(hl);
    for (int i = t; i < NNODES / 4; i += 256) hl4[i] = (s32x4){0, 0, 0, 0};
    __syncthreads();
    int s0 = b * EBLK;
    if (f) {
        const int* d64 = ei + 2 * NEDGES;   // low words at d64[2*i]
        for (int i0 = s0; i0 < s0 + EBLK; i0 += 512) {
            int i = i0 + 2 * t;
            s32x4 v = *reinterpret_cast<const s32x4*>(d64 + 2 * (size_t)i);
            atomicAdd(&hl[v[0]], 1);
            atomicAdd(&hl[v[2]], 1);
        }
    } else {
        const int* d32 = ei + NEDGES;
        for (int i0 = s0; i0 < s0 + EBLK; i0 += 1024) {
            int i = i0 + 4 * t;
            s32x4 v = *reinterpret_cast<const s32x4*>(d32 + i);
            atomicAdd(&hl[v[0]], 1); atomicAdd(&hl[v[1]], 1);
            atomicAdd(&hl[v[2]], 1); atomicAdd(&hl[v[3]], 1);
        }
    }
    __syncthreads();
    s32x4* Hb4 = reinterpret_cast<s32x4*>(H + (size_t)b * NNODES);
    for (int i = t; i < NNODES / 4; i += 256) Hb4[i] = hl4[i];
}

// deg[n] = 1 (self-loop) + sum_b H[b][n]; per-block totals for the tiny scan.
__global__ __launch_bounds__(256) void k_colsum(const int* __restrict__ H,
                                                int* __restrict__ deg,
                                                int* __restrict__ bsum) {
    __shared__ int wred[4];
    int t = threadIdx.x, n = blockIdx.x * 256 + t;
    int s = 0;
    if (n < NNODES) {
#pragma unroll 5
        for (int b = 0; b < NBLK; b++) s += H[(size_t)b * NNODES + n];
        s += 1;  // self-loop
        deg[n] = s;
    }
    int r = s;
#pragma unroll
    for (int o = 1; o < 64; o <<= 1) r += __shfl_xor(r, o);
    if ((t & 63) == 0) wred[t >> 6] = r;
    __syncthreads();
    if (t == 0) bsum[blockIdx.x] = wred[0] + wred[1] + wred[2] + wred[3];
}

// 1 tiny block: exclusive scan of the 79 block sums.
__global__ void k_scansm(const int* __restrict__ bsum, int* __restrict__ boff,
                         int* __restrict__ off) {
    __shared__ int w0tot;
    int t = threadIdx.x, lane = t & 63, w = t >> 6;
    int v = (t < CBLK) ? bsum[t] : 0;
    int sc = v;
#pragma unroll
    for (int o = 1; o < 64; o <<= 1) {
        int u = __shfl_up(sc, o);
        if (lane >= o) sc += u;
    }
    if (w == 0 && lane == 63) w0tot = sc;
    __syncthreads();
    int excl = sc - v + (w ? w0tot : 0);
    if (t < CBLK) boff[t] = excl;
    if (t == 0) off[NNODES] = ETOT;
}

// Per 256-node block: intra-block shuffle scan of deg -> off[n] (coalesced write),
// self-loop csr entry at off[n], then per-block H bases (prefix over NBLK, +1 for
// the reserved self-loop slot).
__global__ __launch_bounds__(256) void k_base(int* __restrict__ H,
                                              const int* __restrict__ deg,
                                              const int* __restrict__ boff,
                                              int* __restrict__ off,
                                              int* __restrict__ csr) {
    __shared__ int wtot[4];
    int t = threadIdx.x, blk = blockIdx.x;
    int n = blk * 256 + t;
    int d = (n < NNODES) ? deg[n] : 0;
    int lane = t & 63, w = t >> 6;
    int sc = d;
#pragma unroll
    for (int o = 1; o < 64; o <<= 1) {
        int u = __shfl_up(sc, o);
        if (lane >= o) sc += u;
    }
    if (lane == 63) wtot[w] = sc;
    __syncthreads();
    int woff = 0;
    for (int i = 0; i < w; i++) woff += wtot[i];
    int excl = woff + sc - d;
    if (n < NNODES) {
        int o0 = boff[blk] + excl;
        off[n] = o0;
        csr[o0] = n;          // self-loop in first slot
        int run = o0 + 1;     // reserve it
#pragma unroll 5
        for (int b = 0; b < NBLK; b++) {
            size_t idx = (size_t)b * NNODES + n;
            int tt = H[idx];
            H[idx] = run;
            run += tt;
        }
    }
}

// Scatter real edges using LDS-staged per-block bases. Zero global atomics.
__global__ __launch_bounds__(256) void k_scatter2(const int* __restrict__ ei,
                                                  const int* __restrict__ H,
                                                  int* __restrict__ csr,
                                                  const int* __restrict__ flag) {
    __shared__ int base_l[NNODES];  // 80 KB
    int t = threadIdx.x, b = blockIdx.x, f = flag[0];
    const s32x4* Hb4 = reinterpret_cast<const s32x4*>(H + (size_t)b * NNODES);
    s32x4* bl4 = reinterpret_cast<s32x4*>(base_l);
    for (int i = t; i < NNODES / 4; i += 256) bl4[i] = Hb4[i];
    __syncthreads();
    int s0 = b * EBLK;
    if (f) {
        const int* d64 = ei + 2 * NEDGES;
        for (int i0 = s0; i0 < s0 + EBLK; i0 += 512) {
            int i = i0 + 2 * t;
            s32x4 sv = *reinterpret_cast<const s32x4*>(ei + 2 * (size_t)i);
            s32x4 dv = *reinterpret_cast<const s32x4*>(d64 + 2 * (size_t)i);
            int p0 = atomicAdd(&base_l[dv[0]], 1);
            csr[p0] = sv[0];
            int p1 = atomicAdd(&base_l[dv[2]], 1);
            csr[p1] = sv[2];
        }
    } else {
        const int* d32 = ei + NEDGES;
        for (int i0 = s0; i0 < s0 + EBLK; i0 += 1024) {
            int i = i0 + 4 * t;
            s32x4 sv = *reinterpret_cast<const s32x4*>(ei + i);
            s32x4 dv = *reinterpret_cast<const s32x4*>(d32 + i);
#pragma unroll
            for (int k = 0; k < 4; k++) {
                int p = atomicAdd(&base_l[dv[k]], 1);
                csr[p] = sv[k];
            }
        }
    }
}

// ---------------- both weight transposes, one launch ----------------
__global__ void k_wt(const void* __restrict__ W1, const void* __restrict__ W2,
                     __hip_bfloat16* __restrict__ Wt1, __hip_bfloat16* __restrict__ Wt2,
                     const int* __restrict__ flag) {
    int i = blockIdx.x * 256 + threadIdx.x;  // 131072
    int which = i >> 16;
    int j = i & 65535;
    int k = j >> 8, n = j & 255;
    const void* W = which ? W2 : W1;
    __hip_bfloat16* Wt = which ? Wt2 : Wt1;
    Wt[(size_t)n * 256 + k] = __float2bfloat16(ldf(W, (size_t)k * 256 + n, flag[1]));
}

// ---------------- GEMM (16-row blocks, wave = one head's 64 cols) ----------------
// Block = 16 rows x 256 cols, 4 waves; wave w owns cols [w*64, w*64+64) == head w.
// Grid = 1250 blocks (4.9 blocks/CU) -> latency hiding via occupancy.
// Head alignment makes the fused es/ed epilogue fully wave-local (no LDS reduce).
// A frag: lane holds A[m=lane&15][k=(lane>>4)*8+j]; B mirrors with n=lane&15.
// D frag: col=lane&15, row=(lane>>4)*4+reg (m89/m91-verified).
__global__ __launch_bounds__(256) void k_gemm(const void* __restrict__ A,
                                              const __hip_bfloat16* __restrict__ Bt,
                                              __hip_bfloat16* __restrict__ Hout,
                                              const void* __restrict__ a_src,
                                              const void* __restrict__ a_dst,
                                              float* __restrict__ es4, float* __restrict__ ed4,
                                              const int* __restrict__ flag, int force_bf) {
    int bf   = flag[1];
    int abf  = force_bf | bf;
    int w    = threadIdx.x >> 6;
    int lane = threadIdx.x & 63;
    int mr   = lane & 15;
    int quad = lane >> 4;
    int r0   = blockIdx.x * 16;
    if (r0 >= NNODES) return;
    f32x4 acc[4];
#pragma unroll
    for (int j = 0; j < 4; j++) acc[j] = (f32x4){0.f, 0.f, 0.f, 0.f};
    size_t rowoff = (size_t)(r0 + mr) * HC;
    const __hip_bfloat16* Btw = Bt + (size_t)w * 64 * HC;
    for (int kk = 0; kk < HC; kk += 32) {
        bf16x8 a;
        if (abf) {
            a = *reinterpret_cast<const bf16x8*>((const __hip_bfloat16*)A + rowoff + kk + quad * 8);
        } else {
            const float* af = (const float*)A + rowoff + kk + quad * 8;
            f32x4 lo = *reinterpret_cast<const f32x4*>(af);
            f32x4 hi = *reinterpret_cast<const f32x4*>(af + 4);
#pragma unroll
            for (int ii = 0; ii < 4; ii++) { a[ii] = f2bs(lo[ii]); a[ii + 4] = f2bs(hi[ii]); }
        }
#pragma unroll
        for (int j = 0; j < 4; j++) {
            bf16x8 b = *reinterpret_cast<const bf16x8*>(Btw + (size_t)(j * 16 + mr) * HC + kk + quad * 8);
            acc[j] = __builtin_amdgcn_mfma_f32_16x16x32_bf16(a, b, acc[j], 0, 0, 0);
        }
    }
    // store H (bf16): cols w*64 + j*16 + mr
#pragma unroll
    for (int j = 0; j < 4; j++)
#pragma unroll
        for (int r = 0; r < 4; r++)
            Hout[(size_t)(r0 + quad * 4 + r) * HC + w * 64 + j * 16 + mr] = __float2bfloat16(acc[j][r]);
    // fused scores for head w only: es[row][w] = sum over head-w cols of h*a_src
    float ps[4] = {0.f, 0.f, 0.f, 0.f}, pd[4] = {0.f, 0.f, 0.f, 0.f};
#pragma unroll
    for (int j = 0; j < 4; j++) {
        float asv = ldf(a_src, (size_t)(w * 64 + j * 16 + mr), bf);
        float adv = ldf(a_dst, (size_t)(w * 64 + j * 16 + mr), bf);
#pragma unroll
        for (int r = 0; r < 4; r++) {
            ps[r] = fmaf(acc[j][r], asv, ps[r]);
            pd[r] = fmaf(acc[j][r], adv, pd[r]);
        }
    }
#pragma unroll
    for (int o = 1; o < 16; o <<= 1)
#pragma unroll
        for (int r = 0; r < 4; r++) {
            ps[r] += __shfl_xor(ps[r], o);
            pd[r] += __shfl_xor(pd[r], o);
        }
    if (mr == 0)
#pragma unroll
        for (int r = 0; r < 4; r++) {
            int row = r0 + quad * 4 + r;
            es4[(size_t)row * 4 + w] = ps[r];
            ed4[(size_t)row * 4 + w] = pd[r];
        }
}

// ---------------- fused softmax + aggregation (wave per node, persistent) ----------------
// Softmax phase: lane j owns edge j of the 64-edge chunk (online, all 4 heads).
// Gather phase: lane covers 8 cols (16B load); half-waves take 8 CONSECUTIVE edges
// -> indices/weights via ds_read_b128 from planar LDS; packed f32x2 accumulate.
__global__ __launch_bounds__(256) void k_agg(const __hip_bfloat16* __restrict__ Hb,
                                             const float* __restrict__ es4, const float* __restrict__ ed4,
                                             const void* __restrict__ bias,
                                             const int* __restrict__ off, const int* __restrict__ csr,
                                             const int* __restrict__ flag,
                                             __hip_bfloat16* __restrict__ out) {
    __shared__ float p_lds[4][4][64];  // [wave][head][edge]
    __shared__ int   s_lds[4][64];
    int wv = threadIdx.x >> 6;
    int l  = threadIdx.x & 63;
    int half = l >> 5;
    int hl   = l & 31;
    int hd8  = hl >> 3;               // head owning cols hl*8..hl*8+7
    int bf = flag[1];
    int n0 = blockIdx.x * 4 + wv;
    for (int n = n0; n < NNODES; n += 10000) {
        int base = off[n], deg = off[n + 1] - base;
        f32x4 edv = *reinterpret_cast<const f32x4*>(ed4 + (size_t)n * 4);
        f32x4 m    = (f32x4){-INFINITY, -INFINITY, -INFINITY, -INFINITY};
        f32x4 dsum = (f32x4){0.f, 0.f, 0.f, 0.f};
        f32x2 acc2[4];
#pragma unroll
        for (int d = 0; d < 4; d++) acc2[d] = (f32x2){0.f, 0.f};
        for (int c0 = 0; c0 < deg; c0 += 64) {
            int cn = min(deg - c0, 64);
            int s = 0;
            f32x4 ev;
            if (l < cn) {
                s = csr[base + c0 + l];
                f32x4 e = *reinterpret_cast<const f32x4*>(es4 + (size_t)s * 4);
#pragma unroll
                for (int h = 0; h < 4; h++) {
                    float t = e[h] + edv[h];
                    ev[h] = (t > 0.f) ? t : 0.2f * t;
                }
            } else {
#pragma unroll
                for (int h = 0; h < 4; h++) ev[h] = -INFINITY;
            }
            s_lds[wv][l] = s;   // pad lanes -> row 0 (weight 0)
            // wave max per head
            f32x4 mc = ev;
#pragma unroll
            for (int o = 32; o; o >>= 1)
#pragma unroll
                for (int h = 0; h < 4; h++) mc[h] = fmaxf(mc[h], __shfl_xor(mc[h], o));
            // online-softmax update
            f32x4 al, pv;
#pragma unroll
            for (int h = 0; h < 4; h++) {
                float nm = fmaxf(m[h], mc[h]);
                al[h] = __expf(m[h] - nm);   // m=-inf on first chunk -> 0
                m[h]  = nm;
            }
#pragma unroll
            for (int h = 0; h < 4; h++) pv[h] = (l < cn) ? __expf(ev[h] - m[h]) : 0.f;
            f32x4 sc = pv;
#pragma unroll
            for (int o = 32; o; o >>= 1)
#pragma unroll
                for (int h = 0; h < 4; h++) sc[h] += __shfl_xor(sc[h], o);
#pragma unroll
            for (int h = 0; h < 4; h++) dsum[h] = dsum[h] * al[h] + sc[h];
            float a8 = al[hd8];
#pragma unroll
            for (int d = 0; d < 4; d++) acc2[d] *= a8;
#pragma unroll
            for (int h = 0; h < 4; h++) p_lds[wv][h][l] = pv[h];
            // gather: half-waves take 8 consecutive edges each, 16 edges/step
            int jn = (cn + 15) & ~15;
            for (int j = 0; j < jn; j += 16) {
                int e0 = j + 8 * half;
                s32x4 sA = *reinterpret_cast<const s32x4*>(&s_lds[wv][e0]);
                s32x4 sB = *reinterpret_cast<const s32x4*>(&s_lds[wv][e0 + 4]);
                f32x4 pA = *reinterpret_cast<const f32x4*>(&p_lds[wv][hd8][e0]);
                f32x4 pB = *reinterpret_cast<const f32x4*>(&p_lds[wv][hd8][e0 + 4]);
                u32x4 hv[8];
#pragma unroll
                for (int i = 0; i < 8; i++) {
                    int sj = (i < 4) ? sA[i & 3] : sB[i & 3];
                    hv[i] = *reinterpret_cast<const u32x4*>(Hb + (size_t)sj * HC + hl * 8);
                }
#pragma unroll
                for (int i = 0; i < 8; i++) {
                    float p = (i < 4) ? pA[i & 3] : pB[i & 3];
#pragma unroll
                    for (int d = 0; d < 4; d++) {
                        unsigned int u = hv[i][d];
                        f32x2 h2;
                        h2.x = __uint_as_float(u << 16);
                        h2.y = __uint_as_float(u & 0xFFFF0000u);
                        acc2[d] += h2 * p;
                    }
                }
            }
        }
        // merge half-accumulators (scaling is wave-uniform)
#pragma unroll
        for (int d = 0; d < 4; d++) {
            acc2[d].x += __shfl_xor(acc2[d].x, 32);
            acc2[d].y += __shfl_xor(acc2[d].y, 32);
        }
        float rinv = 1.0f / fmaxf(dsum[hd8], 1e-16f);
        if (half == 0) {
            bf16x8 ov;
#pragma unroll
            for (int d = 0; d < 4; d++) {
                float v0 = acc2[d].x * rinv + ldf(bias, (size_t)hl * 8 + 2 * d, bf);
                float v1 = acc2[d].y * rinv + ldf(bias, (size_t)hl * 8 + 2 * d + 1, bf);
                ov[2 * d]     = f2bs(fmaxf(v0, 0.f));
                ov[2 * d + 1] = f2bs(fmaxf(v1, 0.f));
            }
            *reinterpret_cast<bf16x8*>(out + (size_t)n * HC + hl * 8) = ov;
        }
    }
}

// ---------------- readout: 4-row-parallel boundary-flush group sums + counts ----------------
__global__ __launch_bounds__(256) void k_groupsum(const __hip_bfloat16* __restrict__ X2,
                                                  const int* __restrict__ batch,
                                                  float* __restrict__ sx, int* __restrict__ cnt,
                                                  const int* __restrict__ flag) {
    const int RPB = NNODES / 250;  // 80
    int b = blockIdx.x, f = flag[0];
    int sub = threadIdx.x >> 6, l = threadIdx.x & 63;
    int r = b * RPB + sub;
    f32x4 acc = (f32x4){0.f, 0.f, 0.f, 0.f};
    int curg = ld_idx(batch, r, f);
    int cacc = 0;
    for (int k = 0; k < RPB / 4; k++, r += 4) {
        int g = ld_idx(batch, r, f);
        if (g != curg) {
#pragma unroll
            for (int c = 0; c < 4; c++) atomicAdd(&sx[(size_t)curg * HC + l * 4 + c], acc[c]);
            if (l == 0) atomicAdd(&cnt[curg], cacc);
            acc = (f32x4){0.f, 0.f, 0.f, 0.f}; cacc = 0; curg = g;
        }
        s16x4 hv = *reinterpret_cast<const s16x4*>(X2 + (size_t)r * HC + l * 4);
#pragma unroll
        for (int c = 0; c < 4; c++) acc[c] += bs2f(hv[c]);
        cacc++;
    }
#pragma unroll
    for (int c = 0; c < 4; c++) atomicAdd(&sx[(size_t)curg * HC + l * 4 + c], acc[c]);
    if (l == 0) atomicAdd(&cnt[curg], cacc);
}

// ---------------- final projection: one block per group, 8-way split dot + LDS reduce --------
__global__ __launch_bounds__(256) void k_final(const float* __restrict__ sx,
                                               const void* __restrict__ Wp,
                                               const void* __restrict__ bp,
                                               const int* __restrict__ cnt,
                                               const int* __restrict__ flag,
                                               void* __restrict__ out) {
    __shared__ float red[8][32];
    int g = blockIdx.x, t = threadIdx.x;
    int c = t & 31, seg = t >> 5;
    int bf = flag[1];
    const float* sxg = sx + (size_t)g * HC;
    float a = 0.f;
#pragma unroll
    for (int k = 0; k < 32; k++) {
        int kk = seg * 32 + k;
        a = fmaf(sxg[kk], ldf(Wp, (size_t)kk * DOUT + c, bf), a);
    }
    red[seg][c] = a;
    __syncthreads();
    if (t < 32) {
        float s = 0.f;
#pragma unroll
        for (int i = 0; i < 8; i++) s += red[i][t];
        int ct = cnt[g];
        float v = (ct > 0) ? (s / ct + ldf(bp, (size_t)t, bf)) : 0.f;
        if (bf) ((__hip_bfloat16*)out)[g * DOUT + t] = __float2bfloat16(v);
        else    ((float*)out)[g * DOUT + t]          = v;
    }
}

extern "C" void kernel_launch(void* const* d_in, const int* in_sizes, int n_in,
                              void* d_out, int out_size, void* d_ws, size_t ws_size,
                              hipStream_t stream) {
    (void)in_sizes; (void)n_in; (void)out_size; (void)ws_size;
    const void* x   = d_in[0];
    const int*  ei  = (const int*)d_in[1];
    const int*  bat = (const int*)d_in[2];
    const void* W1  = d_in[3];
    const void* as1 = d_in[4];
    const void* ad1 = d_in[5];
    const void* b1  = d_in[6];
    const void* W2  = d_in[7];
    const void* as2 = d_in[8];
    const void* ad2 = d_in[9];
    const void* b2  = d_in[10];
    const void* Wp  = d_in[11];
    const void* bp  = d_in[12];

    char* ws = (char*)d_ws;
    size_t o = 0;
    auto alloc = [&](size_t bytes) -> char* {
        char* p = ws + o;
        o += (bytes + 255) & ~(size_t)255;
        return p;
    };
    __hip_bfloat16* hb  = (__hip_bfloat16*)alloc((size_t)NNODES * HC * 2);  // bf16 h
    __hip_bfloat16* xb  = (__hip_bfloat16*)alloc((size_t)NNODES * HC * 2);  // bf16 layer-1 out
    __hip_bfloat16* xb2 = (__hip_bfloat16*)alloc((size_t)NNODES * HC * 2);  // bf16 layer-2 out
    __hip_bfloat16* Wt1 = (__hip_bfloat16*)alloc((size_t)HC * HC * 2);
    __hip_bfloat16* Wt2 = (__hip_bfloat16*)alloc((size_t)HC * HC * 2);
    float* es = (float*)alloc((size_t)NNODES * 4 * 4);
    float* ed = (float*)alloc((size_t)NNODES * 4 * 4);
    int* H    = (int*)alloc((size_t)NBLK * NNODES * 4);    // per-block histograms / bases
    int* deg  = (int*)alloc((size_t)NNODES * 4);
    int* off  = (int*)alloc((size_t)(NNODES + 1) * 4);
    int* csr  = (int*)alloc((size_t)ETOT * 4);
    int* bsum = (int*)alloc((size_t)CBLK * 4);
    int* boff = (int*)alloc((size_t)CBLK * 4);
    float* sx = (float*)alloc((size_t)NGROUP * HC * 4);
    int* cnt  = (int*)alloc(256);
    int* flag = (int*)alloc(256);

    // probe + atomic-free CSR build (shared by both layers)
    k_probe<<<1, 256, 0, stream>>>((const unsigned int*)x, ei, flag, sx, cnt);
    k_lhist<<<NBLK, 256, 0, stream>>>(ei, H, flag);
    k_colsum<<<CBLK, 256, 0, stream>>>(H, deg, bsum);
    k_scansm<<<1, 128, 0, stream>>>(bsum, boff, off);
    k_base<<<CBLK, 256, 0, stream>>>(H, deg, boff, off, csr);
    k_scatter2<<<NBLK, 256, 0, stream>>>(ei, H, csr, flag);
    k_wt<<<512, 256, 0, stream>>>(W1, W2, Wt1, Wt2, flag);

    // Layer 1
    k_gemm<<<NNODES / 16, 256, 0, stream>>>(x, Wt1, hb, as1, ad1, es, ed, flag, 0);
    k_agg<<<2500, 256, 0, stream>>>(hb, es, ed, b1, off, csr, flag, xb);

    // Layer 2
    k_gemm<<<NNODES / 16, 256, 0, stream>>>(xb, Wt2, hb, as2, ad2, es, ed, flag, 1);
    k_agg<<<2500, 256, 0, stream>>>(hb, es, ed, b2, off, csr, flag, xb2);

    // Readout
    k_groupsum<<<250, 256, 0, stream>>>(xb2, bat, sx, cnt, flag);
    k_final<<<NGROUP, 256, 0, stream>>>(sx, Wp, bp, cnt, flag, d_out);
}